// Round 2
// baseline (934.034 us; speedup 1.0000x reference)
//
#include <hip/hip_runtime.h>
#include <hip/hip_bf16.h>

#define N_NODES 100000
#define N_EDGES 1600000

#define NBUCK 391          // ceil(N_NODES / 256)
#define SLAB  4608         // bucket slab capacity (mean 4092, +8 sigma)

// ---------------- CSR build: two-level bucket counting sort ----------------

// Pass A: append each edge into its 256-row bucket slab (packed int2).
__global__ __launch_bounds__(256) void k_bucket(const int* __restrict__ row, const int* __restrict__ col,
                                                const float* __restrict__ val,
                                                int* __restrict__ cursor, int2* __restrict__ slab) {
    int e = blockIdx.x * 256 + threadIdx.x;
    if (e >= N_EDGES) return;
    int r = row[e];
    int b = r >> 8;
    int p = atomicAdd(&cursor[b], 1);
    if (p < SLAB) {
        int2 ent;
        ent.x = ((r & 255) << 24) | col[e];
        ent.y = __float_as_int(val[e]);
        slab[(size_t)b * SLAB + p] = ent;
    }
}

// Exclusive scan of the 391 bucket counts -> bucket CSR base offsets.
__global__ __launch_bounds__(512) void k_bscan(const int* __restrict__ cursor, int* __restrict__ base,
                                               int* __restrict__ row_ptr) {
    __shared__ int s[512];
    int t = threadIdx.x;
    int v = (t < NBUCK) ? cursor[t] : 0;
    s[t] = v;
    __syncthreads();
    for (int st = 1; st < 512; st <<= 1) {
        int u = (t >= st) ? s[t - st] : 0;
        __syncthreads();
        s[t] += u;
        __syncthreads();
    }
    if (t < NBUCK) base[t] = s[t] - v;        // exclusive
    if (t == 0) row_ptr[N_NODES] = N_EDGES;
}

// Pass B: per-bucket LDS counting sort -> final CSR (contiguous region per block)
// and emit row_ptr for the bucket's 256 rows.
__global__ __launch_bounds__(256) void k_sort(const int2* __restrict__ slab, const int* __restrict__ cursor,
                                              const int* __restrict__ base, int* __restrict__ row_ptr,
                                              int2* __restrict__ csr) {
    __shared__ int hist[256];
    __shared__ int cur[256];
    int b = blockIdx.x, t = threadIdx.x;
    int cnt = cursor[b];
    if (cnt > SLAB) cnt = SLAB;
    int bb = base[b];
    hist[t] = 0;
    __syncthreads();
    const int2* sl = slab + (size_t)b * SLAB;
    for (int i = t; i < cnt; i += 256) {
        int rl = ((unsigned)sl[i].x) >> 24;
        atomicAdd(&hist[rl], 1);
    }
    __syncthreads();
    int v = hist[t];
    for (int st = 1; st < 256; st <<= 1) {
        int u = (t >= st) ? hist[t - st] : 0;
        __syncthreads();
        hist[t] += u;
        __syncthreads();
    }
    cur[t] = hist[t] - v;                      // exclusive scan
    int grow = b * 256 + t;
    if (grow < N_NODES) row_ptr[grow] = bb + cur[t];
    __syncthreads();
    for (int i = t; i < cnt; i += 256) {
        int2 e = sl[i];
        int rl = ((unsigned)e.x) >> 24;
        int p = atomicAdd(&cur[rl], 1);
        int2 o;
        o.x = e.x & 0xFFFFFF;
        o.y = e.y;
        csr[bb + p] = o;
    }
}

// ---------------- GEMM1: x[N,256] @ W1[256,32] -> out[N,32] ----------------
__global__ __launch_bounds__(256) void k_gemm1(const float* __restrict__ x, const float* __restrict__ W,
                                               float* __restrict__ out) {
    __shared__ float xs[64][65];
    __shared__ __align__(16) float ws[64 * 32];
    int tid = threadIdx.x;
    int bn = blockIdx.x * 64;
    int tn = tid & 31;
    int to = tid >> 5;
    float acc[2][4] = {};
    for (int kc = 0; kc < 4; ++kc) {
        int k0 = kc * 64;
        #pragma unroll
        for (int i = 0; i < 4; ++i) {
            int idx = i * 256 + tid;
            int n = idx >> 4;
            int k4 = (idx & 15) * 4;
            float4 v = make_float4(0.f, 0.f, 0.f, 0.f);
            if (bn + n < N_NODES)
                v = *reinterpret_cast<const float4*>(&x[(size_t)(bn + n) * 256 + k0 + k4]);
            xs[n][k4 + 0] = v.x; xs[n][k4 + 1] = v.y; xs[n][k4 + 2] = v.z; xs[n][k4 + 3] = v.w;
        }
        #pragma unroll
        for (int i = 0; i < 2; ++i) {
            int idx = i * 256 + tid;
            reinterpret_cast<float4*>(ws)[idx] =
                reinterpret_cast<const float4*>(W + k0 * 32)[idx];
        }
        __syncthreads();
        #pragma unroll 4
        for (int k = 0; k < 64; ++k) {
            float a0 = xs[2 * tn][k];
            float a1 = xs[2 * tn + 1][k];
            float4 w = *reinterpret_cast<const float4*>(&ws[k * 32 + 4 * to]);
            acc[0][0] += a0 * w.x; acc[0][1] += a0 * w.y; acc[0][2] += a0 * w.z; acc[0][3] += a0 * w.w;
            acc[1][0] += a1 * w.x; acc[1][1] += a1 * w.y; acc[1][2] += a1 * w.z; acc[1][3] += a1 * w.w;
        }
        __syncthreads();
    }
    #pragma unroll
    for (int i = 0; i < 2; ++i) {
        int n = bn + 2 * tn + i;
        if (n < N_NODES) {
            float4 r = make_float4(acc[i][0], acc[i][1], acc[i][2], acc[i][3]);
            *reinterpret_cast<float4*>(&out[(size_t)n * 32 + 4 * to]) = r;
        }
    }
}

// ---------------- SpMM (CSR, packed int2): out[n,f] = sum val*sup[col,f] ----------------
template<int F, bool BIASRELU>
__global__ __launch_bounds__(256) void k_spmm(const int* __restrict__ rp, const int2* __restrict__ csr,
                                              const float* __restrict__ sup,
                                              const float* __restrict__ bias, float* __restrict__ out) {
    int gid = blockIdx.x * 256 + threadIdx.x;
    int n = gid / F;
    int f = gid - n * F;
    if (n >= N_NODES) return;
    int e0 = rp[n], e1 = rp[n + 1];
    float acc0 = 0.f, acc1 = 0.f;
    int e = e0;
    for (; e + 1 < e1; e += 2) {
        int2 a = csr[e], b = csr[e + 1];
        acc0 += __int_as_float(a.y) * sup[(size_t)a.x * F + f];
        acc1 += __int_as_float(b.y) * sup[(size_t)b.x * F + f];
    }
    if (e < e1) {
        int2 a = csr[e];
        acc0 += __int_as_float(a.y) * sup[(size_t)a.x * F + f];
    }
    float acc = acc0 + acc1;
    if (BIASRELU) acc = fmaxf(acc + bias[f], 0.f);
    out[(size_t)n * F + f] = acc;
}

// ---------------- small GEMM with bias+relu: g[N,K] @ W[K,M] ----------------
template<int K, int M>
__global__ __launch_bounds__(256) void k_gemm_act(const float* __restrict__ g, const float* __restrict__ W,
                                                  const float* __restrict__ bias, float* __restrict__ out) {
    __shared__ float wsm[K * M];
    __shared__ float bs[M];
    for (int i = threadIdx.x; i < K * M; i += 256) wsm[i] = W[i];
    if (threadIdx.x < M) bs[threadIdx.x] = bias[threadIdx.x];
    __syncthreads();
    int gid = blockIdx.x * 256 + threadIdx.x;
    int n = gid / M;
    int f = gid - n * M;
    if (n >= N_NODES) return;
    const float* gr = g + (size_t)n * K;
    float acc = bs[f];
    #pragma unroll
    for (int k = 0; k < K; ++k) acc += gr[k] * wsm[k * M + f];
    out[(size_t)n * M + f] = fmaxf(acc, 0.f);
}

// ---------------- GEMM3 + global mean pool ----------------
__global__ __launch_bounds__(256) void k_gemm_pool(const float* __restrict__ g, const float* __restrict__ W,
                                                   const float* __restrict__ bias, float* __restrict__ pool) {
    __shared__ float wsm[48 * 64];
    __shared__ float red[256];
    for (int i = threadIdx.x; i < 48 * 64; i += 256) wsm[i] = W[i];
    __syncthreads();
    int f = threadIdx.x & 63;
    int nr = threadIdx.x >> 6;
    float b = bias[f];
    float psum = 0.f;
    int bn = blockIdx.x * 64;
    for (int c = 0; c < 16; ++c) {
        int n = bn + c * 4 + nr;
        if (n < N_NODES) {
            const float* gr = g + (size_t)n * 48;
            float acc = b;
            #pragma unroll
            for (int k = 0; k < 48; ++k) acc += gr[k] * wsm[k * 64 + f];
            psum += fmaxf(acc, 0.f);
        }
    }
    red[threadIdx.x] = psum;
    __syncthreads();
    if (threadIdx.x < 64) {
        float s = red[threadIdx.x] + red[threadIdx.x + 64] + red[threadIdx.x + 128] + red[threadIdx.x + 192];
        atomicAdd(&pool[threadIdx.x], s);
    }
}

// ---------------- head ----------------
__global__ void k_head(const float* __restrict__ pool, const float* __restrict__ fc1W,
                       const float* __restrict__ fc1b, const float* __restrict__ fc2W,
                       const float* __restrict__ fc2b, float* __restrict__ out) {
    __shared__ float z[32];
    __shared__ float lg[2];
    int t = threadIdx.x;
    const float inv = 1.0f / (float)N_NODES;
    if (t < 32) {
        float a = fc1b[t];
        for (int o = 0; o < 64; ++o) a += (pool[o] * inv) * fc1W[o * 32 + t];
        z[t] = fmaxf(a, 0.f);
    }
    __syncthreads();
    if (t < 2) {
        float l = fc2b[t];
        for (int j = 0; j < 32; ++j) l += z[j] * fc2W[j * 2 + t];
        lg[t] = l;
    }
    __syncthreads();
    if (t == 0) {
        float m = fmaxf(lg[0], lg[1]);
        float e0 = __expf(lg[0] - m), e1 = __expf(lg[1] - m);
        float s = e0 + e1;
        out[0] = e0 / s;
        out[1] = e1 / s;
    }
}

// ---------------- launch ----------------

extern "C" void kernel_launch(void* const* d_in, const int* in_sizes, int n_in,
                              void* d_out, int out_size, void* d_ws, size_t ws_size,
                              hipStream_t stream) {
    const float* x    = (const float*)d_in[0];
    const int*   row  = (const int*)d_in[1];
    const int*   col  = (const int*)d_in[2];
    const float* val  = (const float*)d_in[3];
    const float* W1   = (const float*)d_in[4];
    const float* b1   = (const float*)d_in[5];
    const float* W2   = (const float*)d_in[6];
    const float* b2   = (const float*)d_in[7];
    const float* W3   = (const float*)d_in[8];
    const float* b3   = (const float*)d_in[9];
    const float* fc1W = (const float*)d_in[10];
    const float* fc1b = (const float*)d_in[11];
    const float* fc2W = (const float*)d_in[12];
    const float* fc2b = (const float*)d_in[13];
    float* out = (float*)d_out;

    char* wsb = (char*)d_ws;
    size_t off = 0;
    auto alloc = [&](size_t bytes) {
        void* p = wsb + off;
        off += (bytes + 255) / 256 * 256;
        return p;
    };
    int*   cursor  = (int*)alloc((size_t)NBUCK * 4);
    int*   base    = (int*)alloc((size_t)NBUCK * 4);
    int*   row_ptr = (int*)alloc((size_t)(N_NODES + 1) * 4);
    int2*  slab    = (int2*)alloc((size_t)NBUCK * SLAB * 8);
    int2*  csr     = (int2*)alloc((size_t)N_EDGES * 8);
    float* bufA    = (float*)alloc((size_t)N_NODES * 64 * 4);
    float* bufB    = (float*)alloc((size_t)N_NODES * 64 * 4);
    float* pool    = (float*)alloc(64 * 4);

    hipMemsetAsync(cursor, 0, (size_t)NBUCK * 4, stream);
    hipMemsetAsync(pool, 0, 64 * 4, stream);

    // CSR build
    k_bucket<<<(N_EDGES + 255) / 256, 256, 0, stream>>>(row, col, val, cursor, slab);
    k_bscan<<<1, 512, 0, stream>>>(cursor, base, row_ptr);
    k_sort<<<NBUCK, 256, 0, stream>>>(slab, cursor, base, row_ptr, csr);

    // layer 1: support = x@W1 ; h1 = relu(spmm(support)+b1)
    k_gemm1<<<(N_NODES + 63) / 64, 256, 0, stream>>>(x, W1, bufA);
    k_spmm<32, true><<<(N_NODES * 32) / 256, 256, 0, stream>>>(row_ptr, csr, bufA, b1, bufB);
    // layer 2: g2 = spmm(h1) ; h2 = relu(g2@W2+b2)
    k_spmm<32, false><<<(N_NODES * 32) / 256, 256, 0, stream>>>(row_ptr, csr, bufB, nullptr, bufA);
    k_gemm_act<32, 48><<<(N_NODES * 48) / 256, 256, 0, stream>>>(bufA, W2, b2, bufB);
    // layer 3: g3 = spmm(h2) ; pool += relu(g3@W3+b3)
    k_spmm<48, false><<<(N_NODES * 48) / 256, 256, 0, stream>>>(row_ptr, csr, bufB, nullptr, bufA);
    k_gemm_pool<<<(N_NODES + 63) / 64, 256, 0, stream>>>(bufA, W3, b3, pool);
    // head
    k_head<<<1, 64, 0, stream>>>(pool, fc1W, fc1b, fc2W, fc2b, out);
}

// Round 3
// 438.267 us; speedup vs baseline: 2.1312x; 2.1312x over previous
//
#include <hip/hip_runtime.h>
#include <hip/hip_bf16.h>

#define N_NODES 100000
#define N_EDGES 1600000

#define NT 391                               // row buckets of 256 rows
#define NB1 128                              // partition blocks
#define CHUNK ((N_EDGES + NB1 - 1) / NB1)    // 12500 edges per block

// ---------------- CSR build: contention-free two-pass bucket partition ----------------

// Pass 1: per-block LDS histogram of row>>8, dumped to blkhist[j][b].
__global__ __launch_bounds__(256) void k_phist(const int* __restrict__ row, int* __restrict__ blkhist) {
    __shared__ int h[NT];
    int b = blockIdx.x, t = threadIdx.x;
    for (int i = t; i < NT; i += 256) h[i] = 0;
    __syncthreads();
    int s = b * CHUNK, e = min(s + CHUNK, N_EDGES);
    for (int i = s + t; i < e; i += 256) atomicAdd(&h[row[i] >> 8], 1);
    __syncthreads();
    for (int i = t; i < NT; i += 256) blkhist[i * NB1 + b] = h[i];
}

// Pass 2: column-wise exclusive prefix over blocks + bucket base scan.
__global__ __launch_bounds__(512) void k_pscan(int* __restrict__ blkhist, int* __restrict__ base,
                                               int* __restrict__ cnt, int* __restrict__ row_ptr) {
    __shared__ int s[512];
    int j = threadIdx.x;
    int tot = 0;
    if (j < NT) {
        int* colp = blkhist + j * NB1;
        for (int b = 0; b < NB1; ++b) { int v = colp[b]; colp[b] = tot; tot += v; }
    }
    s[j] = (j < NT) ? tot : 0;
    __syncthreads();
    for (int st = 1; st < 512; st <<= 1) {
        int u = (j >= st) ? s[j - st] : 0;
        __syncthreads();
        s[j] += u;
        __syncthreads();
    }
    if (j < NT) {
        int bs = s[j] - tot;                 // exclusive bucket base
        base[j] = bs;
        cnt[j] = tot;
        int* colp = blkhist + j * NB1;
        for (int b = 0; b < NB1; ++b) colp[b] += bs;
    }
    if (j == 0) row_ptr[N_NODES] = N_EDGES;
}

// Pass 3: scatter each edge to its exact final bucket slot (LDS cursors, no global atomics).
__global__ __launch_bounds__(256) void k_pscatter(const int* __restrict__ row, const int* __restrict__ col,
                                                  const float* __restrict__ val,
                                                  const int* __restrict__ blkhist, int2* __restrict__ part) {
    __shared__ int cur[NT];
    int b = blockIdx.x, t = threadIdx.x;
    for (int i = t; i < NT; i += 256) cur[i] = blkhist[i * NB1 + b];
    __syncthreads();
    int s = b * CHUNK, e = min(s + CHUNK, N_EDGES);
    for (int i = s + t; i < e; i += 256) {
        int r = row[i];
        int j = r >> 8;
        int p = atomicAdd(&cur[j], 1);
        part[p] = make_int2(((r & 255) << 24) | col[i], __float_as_int(val[i]));
    }
}

// Pass 4: per-bucket LDS counting sort -> final CSR + row_ptr.
__global__ __launch_bounds__(256) void k_sort(const int2* __restrict__ part, const int* __restrict__ cnt,
                                              const int* __restrict__ base, int* __restrict__ row_ptr,
                                              int2* __restrict__ csr) {
    __shared__ int hist[256];
    __shared__ int cur[256];
    int b = blockIdx.x, t = threadIdx.x;
    int n = cnt[b];
    int bb = base[b];
    const int2* sl = part + bb;
    hist[t] = 0;
    __syncthreads();
    for (int i = t; i < n; i += 256) atomicAdd(&hist[((unsigned)sl[i].x) >> 24], 1);
    __syncthreads();
    int v = hist[t];
    for (int st = 1; st < 256; st <<= 1) {
        int u = (t >= st) ? hist[t - st] : 0;
        __syncthreads();
        hist[t] += u;
        __syncthreads();
    }
    cur[t] = hist[t] - v;                    // exclusive
    int grow = b * 256 + t;
    if (grow < N_NODES) row_ptr[grow] = bb + cur[t];
    __syncthreads();
    for (int i = t; i < n; i += 256) {
        int2 e = sl[i];
        int rl = ((unsigned)e.x) >> 24;
        int p = atomicAdd(&cur[rl], 1);
        csr[bb + p] = make_int2(e.x & 0xFFFFFF, e.y);
    }
}

// ---------------- GEMM1: x[N,256] @ W1[256,32] -> out[N,32] ----------------
__global__ __launch_bounds__(256) void k_gemm1(const float* __restrict__ x, const float* __restrict__ W,
                                               float* __restrict__ out) {
    __shared__ float xs[64][65];
    __shared__ __align__(16) float ws[64 * 32];
    int tid = threadIdx.x;
    int bn = blockIdx.x * 64;
    int tn = tid & 31;
    int to = tid >> 5;
    float acc[2][4] = {};
    for (int kc = 0; kc < 4; ++kc) {
        int k0 = kc * 64;
        #pragma unroll
        for (int i = 0; i < 4; ++i) {
            int idx = i * 256 + tid;
            int n = idx >> 4;
            int k4 = (idx & 15) * 4;
            float4 v = make_float4(0.f, 0.f, 0.f, 0.f);
            if (bn + n < N_NODES)
                v = *reinterpret_cast<const float4*>(&x[(size_t)(bn + n) * 256 + k0 + k4]);
            xs[n][k4 + 0] = v.x; xs[n][k4 + 1] = v.y; xs[n][k4 + 2] = v.z; xs[n][k4 + 3] = v.w;
        }
        #pragma unroll
        for (int i = 0; i < 2; ++i) {
            int idx = i * 256 + tid;
            reinterpret_cast<float4*>(ws)[idx] =
                reinterpret_cast<const float4*>(W + k0 * 32)[idx];
        }
        __syncthreads();
        #pragma unroll 4
        for (int k = 0; k < 64; ++k) {
            float a0 = xs[2 * tn][k];
            float a1 = xs[2 * tn + 1][k];
            float4 w = *reinterpret_cast<const float4*>(&ws[k * 32 + 4 * to]);
            acc[0][0] += a0 * w.x; acc[0][1] += a0 * w.y; acc[0][2] += a0 * w.z; acc[0][3] += a0 * w.w;
            acc[1][0] += a1 * w.x; acc[1][1] += a1 * w.y; acc[1][2] += a1 * w.z; acc[1][3] += a1 * w.w;
        }
        __syncthreads();
    }
    #pragma unroll
    for (int i = 0; i < 2; ++i) {
        int n = bn + 2 * tn + i;
        if (n < N_NODES) {
            float4 r = make_float4(acc[i][0], acc[i][1], acc[i][2], acc[i][3]);
            *reinterpret_cast<float4*>(&out[(size_t)n * 32 + 4 * to]) = r;
        }
    }
}

// ---------------- SpMM (CSR, packed int2) ----------------
template<int F, bool BIASRELU>
__global__ __launch_bounds__(256) void k_spmm(const int* __restrict__ rp, const int2* __restrict__ csr,
                                              const float* __restrict__ sup,
                                              const float* __restrict__ bias, float* __restrict__ out) {
    int gid = blockIdx.x * 256 + threadIdx.x;
    int n = gid / F;
    int f = gid - n * F;
    if (n >= N_NODES) return;
    int e0 = rp[n], e1 = rp[n + 1];
    float acc0 = 0.f, acc1 = 0.f;
    int e = e0;
    for (; e + 1 < e1; e += 2) {
        int2 a = csr[e], b = csr[e + 1];
        acc0 += __int_as_float(a.y) * sup[(size_t)a.x * F + f];
        acc1 += __int_as_float(b.y) * sup[(size_t)b.x * F + f];
    }
    if (e < e1) {
        int2 a = csr[e];
        acc0 += __int_as_float(a.y) * sup[(size_t)a.x * F + f];
    }
    float acc = acc0 + acc1;
    if (BIASRELU) acc = fmaxf(acc + bias[f], 0.f);
    out[(size_t)n * F + f] = acc;
}

// ---------------- small GEMM with bias+relu ----------------
template<int K, int M>
__global__ __launch_bounds__(256) void k_gemm_act(const float* __restrict__ g, const float* __restrict__ W,
                                                  const float* __restrict__ bias, float* __restrict__ out) {
    __shared__ float wsm[K * M];
    __shared__ float bs[M];
    for (int i = threadIdx.x; i < K * M; i += 256) wsm[i] = W[i];
    if (threadIdx.x < M) bs[threadIdx.x] = bias[threadIdx.x];
    __syncthreads();
    int gid = blockIdx.x * 256 + threadIdx.x;
    int n = gid / M;
    int f = gid - n * M;
    if (n >= N_NODES) return;
    const float* gr = g + (size_t)n * K;
    float acc = bs[f];
    #pragma unroll
    for (int k = 0; k < K; ++k) acc += gr[k] * wsm[k * M + f];
    out[(size_t)n * M + f] = fmaxf(acc, 0.f);
}

// ---------------- GEMM3 + global mean pool ----------------
__global__ __launch_bounds__(256) void k_gemm_pool(const float* __restrict__ g, const float* __restrict__ W,
                                                   const float* __restrict__ bias, float* __restrict__ pool) {
    __shared__ float wsm[48 * 64];
    __shared__ float red[256];
    for (int i = threadIdx.x; i < 48 * 64; i += 256) wsm[i] = W[i];
    __syncthreads();
    int f = threadIdx.x & 63;
    int nr = threadIdx.x >> 6;
    float b = bias[f];
    float psum = 0.f;
    int bn = blockIdx.x * 64;
    for (int c = 0; c < 16; ++c) {
        int n = bn + c * 4 + nr;
        if (n < N_NODES) {
            const float* gr = g + (size_t)n * 48;
            float acc = b;
            #pragma unroll
            for (int k = 0; k < 48; ++k) acc += gr[k] * wsm[k * 64 + f];
            psum += fmaxf(acc, 0.f);
        }
    }
    red[threadIdx.x] = psum;
    __syncthreads();
    if (threadIdx.x < 64) {
        float s = red[threadIdx.x] + red[threadIdx.x + 64] + red[threadIdx.x + 128] + red[threadIdx.x + 192];
        atomicAdd(&pool[threadIdx.x], s);
    }
}

// ---------------- head ----------------
__global__ void k_head(const float* __restrict__ pool, const float* __restrict__ fc1W,
                       const float* __restrict__ fc1b, const float* __restrict__ fc2W,
                       const float* __restrict__ fc2b, float* __restrict__ out) {
    __shared__ float z[32];
    __shared__ float lg[2];
    int t = threadIdx.x;
    const float inv = 1.0f / (float)N_NODES;
    if (t < 32) {
        float a = fc1b[t];
        for (int o = 0; o < 64; ++o) a += (pool[o] * inv) * fc1W[o * 32 + t];
        z[t] = fmaxf(a, 0.f);
    }
    __syncthreads();
    if (t < 2) {
        float l = fc2b[t];
        for (int j = 0; j < 32; ++j) l += z[j] * fc2W[j * 2 + t];
        lg[t] = l;
    }
    __syncthreads();
    if (t == 0) {
        float m = fmaxf(lg[0], lg[1]);
        float e0 = __expf(lg[0] - m), e1 = __expf(lg[1] - m);
        float s = e0 + e1;
        out[0] = e0 / s;
        out[1] = e1 / s;
    }
}

// ---------------- launch ----------------

extern "C" void kernel_launch(void* const* d_in, const int* in_sizes, int n_in,
                              void* d_out, int out_size, void* d_ws, size_t ws_size,
                              hipStream_t stream) {
    const float* x    = (const float*)d_in[0];
    const int*   row  = (const int*)d_in[1];
    const int*   col  = (const int*)d_in[2];
    const float* val  = (const float*)d_in[3];
    const float* W1   = (const float*)d_in[4];
    const float* b1   = (const float*)d_in[5];
    const float* W2   = (const float*)d_in[6];
    const float* b2   = (const float*)d_in[7];
    const float* W3   = (const float*)d_in[8];
    const float* b3   = (const float*)d_in[9];
    const float* fc1W = (const float*)d_in[10];
    const float* fc1b = (const float*)d_in[11];
    const float* fc2W = (const float*)d_in[12];
    const float* fc2b = (const float*)d_in[13];
    float* out = (float*)d_out;

    char* wsb = (char*)d_ws;
    size_t off = 0;
    auto alloc = [&](size_t bytes) {
        void* p = wsb + off;
        off += (bytes + 255) / 256 * 256;
        return p;
    };
    int*   blkhist = (int*)alloc((size_t)NT * NB1 * 4);
    int*   base    = (int*)alloc((size_t)NT * 4);
    int*   cnt     = (int*)alloc((size_t)NT * 4);
    int*   row_ptr = (int*)alloc((size_t)(N_NODES + 1) * 4);
    int2*  part    = (int2*)alloc((size_t)N_EDGES * 8);
    int2*  csr     = (int2*)alloc((size_t)N_EDGES * 8);
    float* bufA    = (float*)alloc((size_t)N_NODES * 64 * 4);
    float* bufB    = (float*)alloc((size_t)N_NODES * 64 * 4);
    float* pool    = (float*)alloc(64 * 4);

    hipMemsetAsync(pool, 0, 64 * 4, stream);

    // CSR build (no global atomics anywhere)
    k_phist<<<NB1, 256, 0, stream>>>(row, blkhist);
    k_pscan<<<1, 512, 0, stream>>>(blkhist, base, cnt, row_ptr);
    k_pscatter<<<NB1, 256, 0, stream>>>(row, col, val, blkhist, part);
    k_sort<<<NT, 256, 0, stream>>>(part, cnt, base, row_ptr, csr);

    // layer 1: support = x@W1 ; h1 = relu(spmm(support)+b1)
    k_gemm1<<<(N_NODES + 63) / 64, 256, 0, stream>>>(x, W1, bufA);
    k_spmm<32, true><<<(N_NODES * 32) / 256, 256, 0, stream>>>(row_ptr, csr, bufA, b1, bufB);
    // layer 2: g2 = spmm(h1) ; h2 = relu(g2@W2+b2)
    k_spmm<32, false><<<(N_NODES * 32) / 256, 256, 0, stream>>>(row_ptr, csr, bufB, nullptr, bufA);
    k_gemm_act<32, 48><<<(N_NODES * 48) / 256, 256, 0, stream>>>(bufA, W2, b2, bufB);
    // layer 3: g3 = spmm(h2) ; pool += relu(g3@W3+b3)
    k_spmm<48, false><<<(N_NODES * 48) / 256, 256, 0, stream>>>(row_ptr, csr, bufB, nullptr, bufA);
    k_gemm_pool<<<(N_NODES + 63) / 64, 256, 0, stream>>>(bufA, W3, b3, pool);
    // head
    k_head<<<1, 64, 0, stream>>>(pool, fc1W, fc1b, fc2W, fc2b, out);
}